// Round 3
// baseline (1244.034 us; speedup 1.0000x reference)
//
#include <hip/hip_runtime.h>
#include <hip/hip_bf16.h>
#include <math.h>
#include <string.h>

#define B_   2048
#define TT   128
#define TA   256
#define TV   256
#define CT   300
#define CA   74
#define CV   35
#define D    64
#define E_   4
#define R_   8
#define H_   4
#define L_   4
#define NC   7

// All INPUTS are float32 (reference dtype; confirmed: bf16 reads gave NaN in R1).
// OUTPUT buffer is float32 (confirmed: R2's 3.52 error == my bf16-written `fused`
// values aliasing into the harness's f32 logits region; R0 stub cross-checks).
struct Params {
  const float *text, *audio, *video;
  const float *text_w, *text_b, *text_ln_g, *text_ln_b;
  const float *audio_w, *audio_b, *audio_ln_g, *audio_ln_b;
  const float *video_w, *video_b, *video_ln_g, *video_ln_b;
  const float *latent;
  const float *wq, *bq, *wk, *bk, *wv, *bv, *wo, *bo;
  const float *n1_g, *n1_b, *ffn_w1, *ffn_b1, *ffn_w2, *ffn_b2, *n2_g, *n2_b;
  const float *r_w1, *r_b1, *r_ln_g, *r_ln_b, *r_w2, *r_b2;
  const float *p1_w, *p1_b, *p2_w, *p2_b;
  const float *lora_down, *lora_up;
  const float *c_ln_g, *c_ln_b, *c_w1, *c_b1, *c_w2, *c_b2;
  float *out;
};

// sum across the 64 lanes of a wave (all lanes get the result)
__device__ __forceinline__ float wsum(float v) {
#pragma unroll
  for (int m = 32; m >= 1; m >>= 1) v += __shfl_xor(v, m, 64);
  return v;
}

__global__ __launch_bounds__(256) void perceiver_moe_kernel(Params p) {
  const int b = blockIdx.x;
  const int tid = threadIdx.x;
  const int lane = tid & 63;
  const int wid = tid >> 6;

  __shared__ float s_pool[CT + CA + CV];  // pooled means: text | audio | video
  __shared__ float s_red[256];
  __shared__ float s_z[3 * D];
  __shared__ float s_q[L_ * D];
  __shared__ float s_k[3 * D];
  __shared__ float s_v[3 * D];
  __shared__ float s_attn[H_ * L_ * 3];
  __shared__ float s_ao[L_ * D];
  __shared__ float s_lat1[L_ * D];
  __shared__ float s_h1[L_ * 4 * D];
  __shared__ float s_lat2[L_ * D];
  __shared__ float s_f[D];
  __shared__ float s_rr[D];
  __shared__ float s_rl[E_];
  __shared__ float s_we[E_];
  __shared__ float s_down[E_ * R_];
  __shared__ float s_fused[D];
  __shared__ float s_cl[D];
  __shared__ float s_hh[D];

  // ---------------- pooling: text [128,300] ----------------
  {
    const float *xt = p.text + (size_t)b * TT * CT;
    for (int c = tid; c < CT; c += 256) {
      float s = 0.f;
      for (int t = 0; t < TT; ++t) s += xt[t * CT + c];
      s_pool[c] = s * (1.f / TT);
    }
  }
  // ---------------- pooling: audio [256,74], 3 groups of 74 ----------------
  {
    const float *xa = p.audio + (size_t)b * TA * CA;
    float s = 0.f;
    if (tid < 3 * CA) {
      int g = tid / CA, c = tid % CA;
      for (int t = g; t < TA; t += 3) s += xa[t * CA + c];
    }
    s_red[tid] = s;
    __syncthreads();
    if (tid < CA)
      s_pool[CT + tid] = (s_red[tid] + s_red[CA + tid] + s_red[2 * CA + tid]) * (1.f / TA);
    __syncthreads();  // s_red reused below
  }
  // ---------------- pooling: video [256,35], 7 groups of 35 ----------------
  {
    const float *xv = p.video + (size_t)b * TV * CV;
    float s = 0.f;
    if (tid < 7 * CV) {
      int g = tid / CV, c = tid % CV;
      for (int t = g; t < TV; t += 7) s += xv[t * CV + c];
    }
    s_red[tid] = s;
    __syncthreads();
    if (tid < CV) {
      float acc = 0.f;
#pragma unroll
      for (int g = 0; g < 7; ++g) acc += s_red[g * CV + tid];
      s_pool[CT + CA + tid] = acc * (1.f / TV);
    }
  }
  __syncthreads();

  // ---------------- modality projections + LN + ReLU: wave w = modality w ----------------
  if (wid < 3) {
    const float *W, *bb, *g, *be;
    int Cin, off;
    if (wid == 0) { W = p.text_w;  bb = p.text_b;  g = p.text_ln_g;  be = p.text_ln_b;  Cin = CT; off = 0; }
    else if (wid == 1) { W = p.audio_w; bb = p.audio_b; g = p.audio_ln_g; be = p.audio_ln_b; Cin = CA; off = CT; }
    else { W = p.video_w; bb = p.video_b; g = p.video_ln_g; be = p.video_ln_b; Cin = CV; off = CT + CA; }
    float acc = bb[lane];
    for (int i = 0; i < Cin; ++i) acc += s_pool[off + i] * W[i * D + lane];
    float m = wsum(acc) * (1.f / D);
    float d = acc - m;
    float v = wsum(d * d) * (1.f / D);
    float z = d * rsqrtf(v + 1e-5f) * g[lane] + be[lane];
    s_z[wid * D + lane] = fmaxf(z, 0.f);
  }
  __syncthreads();

  // ---------------- q (4 waves: l=wid), k & v (waves 0..2: s=wid) ----------------
  {
    float acc = p.bq[lane];
    for (int i = 0; i < D; ++i) acc += p.latent[wid * D + i] * p.wq[i * D + lane];
    s_q[wid * D + lane] = acc;
  }
  if (wid < 3) {
    float ak = p.bk[lane];
    float av = p.bv[lane];
    for (int i = 0; i < D; ++i) {
      float z = s_z[wid * D + i];
      ak += z * p.wk[i * D + lane];
      av += z * p.wv[i * D + lane];
    }
    s_k[wid * D + lane] = ak;
    s_v[wid * D + lane] = av;
  }
  __syncthreads();

  // ---------------- scores + softmax (16 threads: h,l) ----------------
  if (tid < H_ * L_) {
    int h = tid >> 2, l = tid & 3;
    float sc[3];
    float mx = -1e30f;
#pragma unroll
    for (int s = 0; s < 3; ++s) {
      float a = 0.f;
#pragma unroll
      for (int d2 = 0; d2 < 16; ++d2)
        a += s_q[l * D + h * 16 + d2] * s_k[s * D + h * 16 + d2];
      sc[s] = a * 0.25f;  // / sqrt(16)
      mx = fmaxf(mx, sc[s]);
    }
    float den = 0.f;
#pragma unroll
    for (int s = 0; s < 3; ++s) { sc[s] = expf(sc[s] - mx); den += sc[s]; }
    float inv = 1.f / den;
#pragma unroll
    for (int s = 0; s < 3; ++s) s_attn[(h * L_ + l) * 3 + s] = sc[s] * inv;
  }
  __syncthreads();

  // ---------------- attn @ v  (l=wid, j=lane) ----------------
  {
    int h = lane >> 4;
    float a = 0.f;
#pragma unroll
    for (int s = 0; s < 3; ++s) a += s_attn[(h * L_ + wid) * 3 + s] * s_v[s * D + lane];
    s_ao[wid * D + lane] = a;
  }
  __syncthreads();

  // ---------------- out-proj + residual + LN1 ----------------
  {
    float acc = p.bo[lane];
    for (int i = 0; i < D; ++i) acc += s_ao[wid * D + i] * p.wo[i * D + lane];
    float x = p.latent[wid * D + lane] + acc;
    float m = wsum(x) * (1.f / D);
    float d = x - m;
    float v = wsum(d * d) * (1.f / D);
    s_lat1[wid * D + lane] = d * rsqrtf(v + 1e-5f) * p.n1_g[lane] + p.n1_b[lane];
  }
  __syncthreads();

  // ---------------- FFN1 + exact GELU (thread = column m of 256) ----------------
  {
    float bb1 = p.ffn_b1[tid];
    float accf[L_];
#pragma unroll
    for (int l = 0; l < L_; ++l) accf[l] = bb1;
    for (int i = 0; i < D; ++i) {
      float w = p.ffn_w1[i * 256 + tid];
#pragma unroll
      for (int l = 0; l < L_; ++l) accf[l] += s_lat1[l * D + i] * w;
    }
#pragma unroll
    for (int l = 0; l < L_; ++l) {
      float x = accf[l];
      s_h1[l * 256 + tid] = 0.5f * x * (1.f + erff(x * 0.70710678118654752f));
    }
  }
  __syncthreads();

  // ---------------- FFN2 + residual + LN2 (l=wid, j=lane) ----------------
  {
    float acc = p.ffn_b2[lane];
    for (int m2 = 0; m2 < 256; ++m2) acc += s_h1[wid * 256 + m2] * p.ffn_w2[m2 * D + lane];
    float x = s_lat1[wid * D + lane] + acc;
    float m = wsum(x) * (1.f / D);
    float d = x - m;
    float v = wsum(d * d) * (1.f / D);
    s_lat2[wid * D + lane] = d * rsqrtf(v + 1e-5f) * p.n2_g[lane] + p.n2_b[lane];
  }
  __syncthreads();

  // ---------------- f = mean over latents; output 3 ----------------
  if (tid < D) {
    float f = 0.25f * (s_lat2[tid] + s_lat2[D + tid] + s_lat2[2 * D + tid] + s_lat2[3 * D + tid]);
    s_f[tid] = f;
    p.out[(size_t)B_ * 75 + (size_t)b * D + tid] = f;
  }
  __syncthreads();

  // ---------------- router branch / views / lora-down in parallel by wave ----------------
  if (wid == 0) {
    float acc = p.r_b1[lane];
    for (int i = 0; i < D; ++i) acc += s_f[i] * p.r_w1[i * D + lane];
    float m = wsum(acc) * (1.f / D);
    float d = acc - m;
    float v = wsum(d * d) * (1.f / D);
    float z = d * rsqrtf(v + 1e-5f) * p.r_ln_g[lane] + p.r_ln_b[lane];
    s_rr[lane] = fmaxf(z, 0.f);
  } else if (wid == 1) {
    if (lane < 32) {
      float acc = p.p1_b[lane];
      for (int i = 0; i < D; ++i) acc += s_f[i] * p.p1_w[i * 32 + lane];
      p.out[(size_t)B_ * 139 + (size_t)b * 32 + lane] = acc;
    }
  } else if (wid == 2) {
    if (lane < 32) {
      float acc = p.p2_b[lane];
      for (int i = 0; i < D; ++i) acc += s_f[i] * p.p2_w[i * 32 + lane];
      p.out[(size_t)B_ * 171 + (size_t)b * 32 + lane] = acc;
    }
  } else {
    if (lane < E_ * R_) {
      int e = lane >> 3, r = lane & 7;
      float acc = 0.f;
      for (int dd = 0; dd < D; ++dd) acc += s_f[dd] * p.lora_down[e * D * R_ + dd * R_ + r];
      s_down[lane] = acc;
    }
  }
  __syncthreads();

  // ---------------- router logits + softmax; output 1 ----------------
  if (tid < E_) {
    float acc = p.r_b2[tid];
    for (int j = 0; j < D; ++j) acc += s_rr[j] * p.r_w2[j * E_ + tid];
    s_rl[tid] = acc;
  }
  __syncthreads();
  if (tid == 0) {
    float mx = fmaxf(fmaxf(s_rl[0], s_rl[1]), fmaxf(s_rl[2], s_rl[3]));
    float e0 = expf(s_rl[0] - mx), e1 = expf(s_rl[1] - mx);
    float e2 = expf(s_rl[2] - mx), e3 = expf(s_rl[3] - mx);
    float inv = 1.f / (e0 + e1 + e2 + e3);
    s_we[0] = e0 * inv; s_we[1] = e1 * inv; s_we[2] = e2 * inv; s_we[3] = e3 * inv;
  }
  __syncthreads();
  if (tid < E_)
    p.out[(size_t)B_ * 7 + (size_t)b * E_ + tid] = s_we[tid];

  // ---------------- LoRA up + expert mix; output 2 (fused) ----------------
  if (tid < D) {
    float f = s_f[tid];
    float acc = 0.f;
#pragma unroll
    for (int e = 0; e < E_; ++e) {
      float up = 0.f;
#pragma unroll
      for (int r = 0; r < R_; ++r)
        up += s_down[e * R_ + r] * p.lora_up[e * R_ * D + r * D + tid];
      acc += s_we[e] * (f + 2.0f * up);  // SCALING = 16/8 = 2
    }
    s_fused[tid] = acc;
    p.out[(size_t)B_ * 11 + (size_t)b * D + tid] = acc;
  }
  __syncthreads();

  // ---------------- classifier ----------------
  if (wid == 0) {
    float x = s_fused[lane];
    float m = wsum(x) * (1.f / D);
    float d = x - m;
    float v = wsum(d * d) * (1.f / D);
    s_cl[lane] = d * rsqrtf(v + 1e-5f) * p.c_ln_g[lane] + p.c_ln_b[lane];
  }
  __syncthreads();
  if (wid == 0) {
    float acc = p.c_b1[lane];
    for (int i = 0; i < D; ++i) acc += s_cl[i] * p.c_w1[i * D + lane];
    s_hh[lane] = fmaxf(acc, 0.f);
  }
  __syncthreads();
  if (tid < NC) {
    float acc = p.c_b2[tid];
    for (int j = 0; j < D; ++j) acc += s_hh[j] * p.c_w2[j * NC + tid];
    p.out[(size_t)b * NC + tid] = acc;
  }
}

extern "C" void kernel_launch(void* const* d_in, const int* in_sizes, int n_in,
                              void* d_out, int out_size, void* d_ws, size_t ws_size,
                              hipStream_t stream) {
  (void)in_sizes; (void)n_in; (void)out_size; (void)d_ws; (void)ws_size;
  Params p;
  // Params is 50 const pointers in exact setup_inputs() order, then out.
  memcpy(&p, d_in, 50 * sizeof(void*));
  p.out = (float*)d_out;
  perceiver_moe_kernel<<<dim3(B_), dim3(256), 0, stream>>>(p);
}